// Round 7
// baseline (732.352 us; speedup 1.0000x reference)
//
#include <hip/hip_runtime.h>
#include <hip/hip_bf16.h>

// LoRALinear: out = x @ (W + 2.0*B@A)^T + bias ; M=16384, N=4096, K=4096, R=16.
// Round 7: B operand bypasses LDS. W_eff is stored by the prep kernel in
// FRAGMENT-LINEAR order (16x32 frag = 1KB, lane l at frag*1024 + l*16), so a
// wave's B-frag load is one coalesced 1KB global_load_dwordx4 from L2/L3.
// LDS now holds only A (2 x 32KB dbuf). Per K-tile/CU: LDS reads 192->128,
// LDS writes 64->32KB, barriers 2->1. B(t+1) prefetched into alternating
// register sets (static names, rule #20) a full K-tile ahead.
// ws layout: [0,134217728) x_bf16 ; [134217728, +33554432) W_eff_tiled_bf16.

typedef __attribute__((ext_vector_type(8))) short bf16x8;
typedef __attribute__((ext_vector_type(4))) float f32x4;
typedef __attribute__((ext_vector_type(4))) unsigned short u16x4;

#define M_DIM 16384
#define N_DIM 4096
#define K_DIM 4096
#define NT 64   // K-tiles of BK=64

__device__ __forceinline__ unsigned short f2bf(float f) {
    unsigned int u = __builtin_bit_cast(unsigned int, f);
    unsigned int r = u + 0x7FFFu + ((u >> 16) & 1u);
    return (unsigned short)(r >> 16);
}

__device__ __forceinline__ void async16(const void* g, void* l) {
    __builtin_amdgcn_global_load_lds(
        (const __attribute__((address_space(1))) unsigned int*)g,
        (__attribute__((address_space(3))) unsigned int*)l,
        16, 0, 0);
}

// ---------------- prep kernel 1: x fp32 -> bf16 ----------------
__global__ void __launch_bounds__(256) cast_x_kernel(
    const float4* __restrict__ x, u16x4* __restrict__ y, int n4) {
    int i = blockIdx.x * blockDim.x + threadIdx.x;
    int stride = gridDim.x * blockDim.x;
    for (; i < n4; i += stride) {
        float4 v = x[i];
        u16x4 o = { f2bf(v.x), f2bf(v.y), f2bf(v.z), f2bf(v.w) };
        y[i] = o;
    }
}

// ---------------- prep kernel 2: W_eff = W + 2*B@A -> fragment-tiled bf16 ----
// Element (n,k) -> frag = (n>>4)*128 + (k>>5); lane = (n&15) + ((k>>3)&3)*16;
// elem = k&7; flat = frag*512 + lane*8 + elem  (elements; frag = 1KB).
__global__ void __launch_bounds__(256) weff_kernel(
    const float* __restrict__ W, const float* __restrict__ lA,
    const float* __restrict__ lB, unsigned short* __restrict__ out) {
    constexpr int K = K_DIM, R = 16;
    constexpr float S = 2.0f;  // 32.0 / 16
    int o = blockIdx.x;
    int t = threadIdx.x;
    float b[R];
#pragma unroll
    for (int r = 0; r < R; ++r) b[r] = lB[o * R + r];
#pragma unroll
    for (int c = 0; c < 4; ++c) {
        int i = c * 1024 + t * 4;  // k base, 4-aligned
        float4 wv = *reinterpret_cast<const float4*>(&W[o * K + i]);
        float sx = 0.f, sy = 0.f, sz = 0.f, sw = 0.f;
#pragma unroll
        for (int r = 0; r < R; ++r) {
            float4 a = *reinterpret_cast<const float4*>(&lA[r * K + i]);
            sx += b[r] * a.x; sy += b[r] * a.y;
            sz += b[r] * a.z; sw += b[r] * a.w;
        }
        u16x4 ov = { f2bf(wv.x + S * sx), f2bf(wv.y + S * sy),
                     f2bf(wv.z + S * sz), f2bf(wv.w + S * sw) };
        const int frag = (o >> 4) * 128 + (i >> 5);
        const int lane_ = (o & 15) + (((i >> 3) & 3) << 4);
        const size_t addr = ((size_t)frag << 9) + (lane_ << 3) + (i & 7);
        *reinterpret_cast<u16x4*>(&out[addr]) = ov;
    }
}

// ---------------- main GEMM: 256x256 tile, 8-wave, 16x16x32 MFMA ----------------
// LDS: A only, 2 x 32KB dbuf, 128B rows XOR-swizzled (round-2 pattern,
// measured 0 conflicts). B: direct global->VGPR from fragment-tiled layout.
#define STAGE(G, h, tt, bsel)                                                 \
    do {                                                                      \
        const unsigned short* g0 = (G) +                                      \
            (size_t)((h) * 128 + wid * 16 + rc) * K_DIM + (tt) * 64 + cc * 8; \
        char* l0 = lds + (bsel) * 32768 + (h) * 16384 + wid * 2048;           \
        async16(g0, l0);                                                      \
        async16(g0 + 8 * K_DIM, l0 + 1024);                                   \
    } while (0)

#define LDA_TO(dst, mh, bsel)                                                 \
    _Pragma("unroll") for (int mm = 0; mm < 4; ++mm)                          \
    _Pragma("unroll") for (int ks = 0; ks < 2; ++ks)                          \
        dst[mm][ks] = *(const bf16x8*)(lds + (bsel) * 32768 +                 \
            ((aBase + ((mh) * 4 + mm) * 2048) ^ (ks << 6)));

// 8 coalesced 1KB fragment loads: frag (bgrp+j, tt*2+ks), lane offset l*16B
#define LOADB(dst, tt)                                                        \
    _Pragma("unroll") for (int j = 0; j < 4; ++j)                             \
    _Pragma("unroll") for (int ks = 0; ks < 2; ++ks)                          \
        dst[j][ks] = *(const bf16x8*)(Bt +                                    \
            (((size_t)(bgrp + j) * 128 + (tt) * 2 + ks) << 9) + (lane << 3));

// one m-half: 32 MFMA over (mm 0..3) x (j 0..3) x (ks 0..1)
#define MMH(mh, BR)                                                           \
    __builtin_amdgcn_s_setprio(1);                                            \
    _Pragma("unroll") for (int ks = 0; ks < 2; ++ks)                          \
    _Pragma("unroll") for (int mm = 0; mm < 4; ++mm)                          \
    _Pragma("unroll") for (int j = 0; j < 4; ++j)                             \
        acc[(mh) * 4 + mm][j] = __builtin_amdgcn_mfma_f32_16x16x32_bf16(      \
            ar[mm][ks], BR[j][ks], acc[(mh) * 4 + mm][j], 0, 0, 0);           \
    __builtin_amdgcn_s_setprio(0)

#define CFENCE() asm volatile("" ::: "memory")

// one K-tile: issue A(t+1) stage + B(t+1) loads, compute from bs + BRCUR,
// boundary = counted vmcnt(8) (retires A(t+1), keeps B(t+1)) + ONE barrier.
#define KTILE(t, BRCUR, BRNXT)                                                \
    {                                                                         \
        const int bs_ = (t) & 1, bo_ = bs_ ^ 1;                               \
        if ((t) + 1 < NT) {                                                   \
            STAGE(Ag, 0, (t) + 1, bo_);                                       \
            STAGE(Ag, 1, (t) + 1, bo_);                                       \
            CFENCE(); /* pin order: A stages BEFORE B loads (vmcnt count) */  \
            LOADB(BRNXT, (t) + 1);                                            \
        }                                                                     \
        CFENCE();                                                             \
        LDA_TO(ar, 0, bs_);                                                   \
        MMH(0, BRCUR);                                                        \
        LDA_TO(ar, 1, bs_);                                                   \
        MMH(1, BRCUR);                                                        \
        if ((t) + 1 < NT) {                                                   \
            asm volatile("s_waitcnt vmcnt(8)" ::: "memory");                  \
            __builtin_amdgcn_s_barrier();                                     \
            CFENCE();                                                         \
        }                                                                     \
    }

__global__ void __launch_bounds__(512, 2) gemmbd_kernel(
    const unsigned short* __restrict__ A,
    const unsigned short* __restrict__ Bt,
    const float* __restrict__ bias,
    float* __restrict__ C) {
    __shared__ __align__(1024) char lds[65536];

    const int tid = threadIdx.x;
    const int lane = tid & 63, wid = tid >> 6;
    const int wm = wid >> 2, wn = wid & 3;   // 2 x 4 waves
    const int lr = lane & 15, lg = lane >> 4;

    // round-2 mapping: 1024 blocks, XCD-aware swizzle
    const int bid = blockIdx.x;
    const int swz = (bid & 7) * 128 + (bid >> 3);
    const int bm = swz >> 4, bn = swz & 15;  // 64 x 16 tiles

    const unsigned short* Ag = A + (size_t)bm * 256 * K_DIM;
    const int bgrp = bn * 16 + wn * 4;       // B fragment n-group base

    // staging lane pre-swizzle (inverse of the read XOR)
    const int lam = lane ^ (lane >> 3);
    const int rc = lam >> 3, cc = lam & 7;

    // read-side swizzled A base
    const int kx0 = (lg * 16) ^ ((lr & 7) << 4);
    const int aBase = (wm * 128 + lr) * 128 + kx0;

    f32x4 acc[8][4] = {};
    bf16x8 ar[4][2], brX[4][2], brY[4][2];

    // prologue: A(0)->buf0 (4 async16), B(0)->brX (8 loads)
    STAGE(Ag, 0, 0, 0);
    STAGE(Ag, 1, 0, 0);
    CFENCE();
    LOADB(brX, 0);
    asm volatile("s_waitcnt vmcnt(8)" ::: "memory");  // retire A(0)
    __builtin_amdgcn_s_barrier();
    CFENCE();

    for (int tt = 0; tt < NT; tt += 2) {
        KTILE(tt, brX, brY);
        KTILE(tt + 1, brY, brX);
    }

    // epilogue: D col = lane&15, row = (lane>>4)*4 + r (verified m89/m91)
    const int row0 = bm * 256 + wm * 128;
    const int col0 = bn * 256 + wn * 64;
#pragma unroll
    for (int n = 0; n < 4; ++n) {
        const int col = col0 + n * 16 + lr;
        const float bv = bias[col];
#pragma unroll
        for (int m = 0; m < 8; ++m) {
            const int r0 = row0 + m * 16 + lg * 4;
#pragma unroll
            for (int r = 0; r < 4; ++r)
                C[(size_t)(r0 + r) * N_DIM + col] = acc[m][n][r] + bv;
        }
    }
}

extern "C" void kernel_launch(void* const* d_in, const int* in_sizes, int n_in,
                              void* d_out, int out_size, void* d_ws, size_t ws_size,
                              hipStream_t stream) {
    const float* x    = (const float*)d_in[0];  // [4,4096,4096]
    const float* W    = (const float*)d_in[1];  // [4096,4096]
    const float* bias = (const float*)d_in[2];  // [4096]
    const float* lA   = (const float*)d_in[3];  // [16,4096]
    const float* lB   = (const float*)d_in[4];  // [4096,16]
    float* out = (float*)d_out;

    unsigned short* xb   = (unsigned short*)d_ws;                       // 134 MB
    unsigned short* weff = (unsigned short*)((char*)d_ws + 134217728);  // 32 MB

    cast_x_kernel<<<2048, 256, 0, stream>>>((const float4*)x, (u16x4*)xb,
                                            M_DIM * K_DIM / 4);
    weff_kernel<<<N_DIM, 256, 0, stream>>>(W, lA, lB, weff);
    gemmbd_kernel<<<(M_DIM / 256) * (N_DIM / 256), 512, 0, stream>>>(
        xb, weff, bias, out);
}

// Round 8
// 677.642 us; speedup vs baseline: 1.0807x; 1.0807x over previous
//
#include <hip/hip_runtime.h>
#include <hip/hip_bf16.h>

// LoRALinear: out = x @ (W + 2.0*B@A)^T + bias ; M=16384, N=4096, K=4096, R=16.
// Round 8: single-barrier K-loop. r7 (B-direct) regressed (620us, MfmaUtil 39)
// -> reverted to r6 base (484us). Change vs r6: stage BOTH A(t+1) and B(t+1)
// at the K-tile TOP into the other dbuf half; ONE vmcnt(0)+barrier at the
// bottom (wait is ~2500cyc after issue -> drain ~free). Mid-tile END-1
// barrier eliminated (no t+2 staging horizon). Waves can slide a full tile.
// ws layout: [0,134217728) x_bf16 ; [134217728, +33554432) W_eff_bf16.

typedef __attribute__((ext_vector_type(8))) short bf16x8;
typedef __attribute__((ext_vector_type(4))) float f32x4;
typedef __attribute__((ext_vector_type(4))) unsigned short u16x4;

#define M_DIM 16384
#define N_DIM 4096
#define K_DIM 4096
#define NT 64   // K-tiles of BK=64

__device__ __forceinline__ unsigned short f2bf(float f) {
    unsigned int u = __builtin_bit_cast(unsigned int, f);
    unsigned int r = u + 0x7FFFu + ((u >> 16) & 1u);
    return (unsigned short)(r >> 16);
}

__device__ __forceinline__ void async16(const void* g, void* l) {
    __builtin_amdgcn_global_load_lds(
        (const __attribute__((address_space(1))) unsigned int*)g,
        (__attribute__((address_space(3))) unsigned int*)l,
        16, 0, 0);
}

// ---------------- prep kernel 1: x fp32 -> bf16 ----------------
__global__ void __launch_bounds__(256) cast_x_kernel(
    const float4* __restrict__ x, u16x4* __restrict__ y, int n4) {
    int i = blockIdx.x * blockDim.x + threadIdx.x;
    int stride = gridDim.x * blockDim.x;
    for (; i < n4; i += stride) {
        float4 v = x[i];
        u16x4 o = { f2bf(v.x), f2bf(v.y), f2bf(v.z), f2bf(v.w) };
        y[i] = o;
    }
}

// ---------------- prep kernel 2: W_eff = W + 2*B@A -> bf16 ----------------
__global__ void __launch_bounds__(256) weff_kernel(
    const float* __restrict__ W, const float* __restrict__ lA,
    const float* __restrict__ lB, unsigned short* __restrict__ out) {
    constexpr int K = K_DIM, R = 16;
    constexpr float S = 2.0f;  // 32.0 / 16
    int o = blockIdx.x;
    int t = threadIdx.x;
    float b[R];
#pragma unroll
    for (int r = 0; r < R; ++r) b[r] = lB[o * R + r];
#pragma unroll
    for (int c = 0; c < 4; ++c) {
        int i = c * 1024 + t * 4;
        float4 wv = *reinterpret_cast<const float4*>(&W[o * K + i]);
        float sx = 0.f, sy = 0.f, sz = 0.f, sw = 0.f;
#pragma unroll
        for (int r = 0; r < R; ++r) {
            float4 a = *reinterpret_cast<const float4*>(&lA[r * K + i]);
            sx += b[r] * a.x; sy += b[r] * a.y;
            sz += b[r] * a.z; sw += b[r] * a.w;
        }
        u16x4 ov = { f2bf(wv.x + S * sx), f2bf(wv.y + S * sy),
                     f2bf(wv.z + S * sz), f2bf(wv.w + S * sw) };
        *reinterpret_cast<u16x4*>(&out[o * K + i]) = ov;
    }
}

// ---------------- main GEMM: 256x256 tile, 8-wave, 16x16x32 MFMA ----------------
// LDS (x2 dbuf): A tile 256x64 bf16 [0,32768) + B tile [32768,65536) per buf,
// 128B rows, XOR-swizzled: phys = row*128 + (colbyte ^ ((row&7)<<4)).
// Stage linear via global_load_lds with lane-pre-swizzled global source.
#define STAGE(G, h, tt, bsel, moff)                                           \
    do {                                                                      \
        const unsigned short* g0 = (G) +                                      \
            (size_t)((h) * 128 + wid * 16 + rc) * K_DIM + (tt) * 64 + cc * 8; \
        char* l0 = lds + (bsel) * 65536 + (moff) + (h) * 16384 + wid * 2048;  \
        async16(g0, l0);                                                      \
        async16(g0 + 8 * K_DIM, l0 + 1024);                                   \
    } while (0)

// fragment reads (round-2 pattern: measured 0 bank conflicts)
#define LDA_TO(dst, mh, bsel)                                                 \
    _Pragma("unroll") for (int mm = 0; mm < 4; ++mm)                          \
    _Pragma("unroll") for (int ks = 0; ks < 2; ++ks)                          \
        dst[mm][ks] = *(const bf16x8*)(lds + (bsel) * 65536 +                 \
            ((aBase + ((mh) * 4 + mm) * 2048) ^ (ks << 6)));

#define LDB_TO(nh, bsel)                                                      \
    _Pragma("unroll") for (int nn = 0; nn < 2; ++nn)                          \
    _Pragma("unroll") for (int ks = 0; ks < 2; ++ks)                          \
        br[(nh) * 2 + nn][ks] = *(const bf16x8*)(lds + (bsel) * 65536 +       \
            ((bBase + ((nh) * 2 + nn) * 2048) ^ (ks << 6)));

// one output quadrant: 16 MFMA using A-set `src` (mh) x B half (nh)
#define MM_Q(src, mh, nh)                                                     \
    __builtin_amdgcn_s_setprio(1);                                            \
    _Pragma("unroll") for (int ks = 0; ks < 2; ++ks)                          \
    _Pragma("unroll") for (int mm = 0; mm < 4; ++mm)                          \
    _Pragma("unroll") for (int nn = 0; nn < 2; ++nn)                          \
        acc[(mh) * 4 + mm][(nh) * 2 + nn] =                                   \
            __builtin_amdgcn_mfma_f32_16x16x32_bf16(                          \
                src[mm][ks], br[(nh) * 2 + nn][ks],                           \
                acc[(mh) * 4 + mm][(nh) * 2 + nn], 0, 0, 0);                  \
    __builtin_amdgcn_s_setprio(0)

#define CFENCE() asm volatile("" ::: "memory")

// one K-tile: stage everything for t+1 at the TOP (into bo), compute from bs,
// ONE vmcnt(0)+barrier at the bottom (wait ~2500cyc after issue -> ~free).
#define KTILE(t)                                                              \
    {                                                                         \
        const int bs_ = (t) & 1, bo_ = bs_ ^ 1;                               \
        if ((t) + 1 < NT) {                                                   \
            STAGE(Ag, 0, (t) + 1, bo_, 0);                                    \
            STAGE(Ag, 1, (t) + 1, bo_, 0);                                    \
            STAGE(Bg, 0, (t) + 1, bo_, 32768);                                \
            STAGE(Bg, 1, (t) + 1, bo_, 32768);                                \
        }                                                                     \
        LDA_TO(arA, 0, bs_);                                                  \
        LDB_TO(0, bs_);                                                       \
        LDB_TO(1, bs_);                                                       \
        MM_Q(arA, 0, 0);                                                      \
        LDA_TO(arB, 1, bs_);                                                  \
        MM_Q(arA, 0, 1);                                                      \
        MM_Q(arB, 1, 0);                                                      \
        MM_Q(arB, 1, 1);                                                      \
        asm volatile("s_waitcnt vmcnt(0)" ::: "memory");                      \
        __builtin_amdgcn_s_barrier();                                         \
        CFENCE();                                                             \
    }

__global__ void __launch_bounds__(512, 2) gemm1b_kernel(
    const unsigned short* __restrict__ A,
    const unsigned short* __restrict__ B,
    const float* __restrict__ bias,
    float* __restrict__ C) {
    __shared__ __align__(1024) char lds[131072];

    const int tid = threadIdx.x;
    const int lane = tid & 63, wid = tid >> 6;
    const int wm = wid >> 2, wn = wid & 3;   // 2 x 4 waves
    const int lr = lane & 15, lg = lane >> 4;

    // round-2 mapping: 1024 blocks, XCD-aware swizzle
    const int bid = blockIdx.x;
    const int swz = (bid & 7) * 128 + (bid >> 3);
    const int bm = swz >> 4, bn = swz & 15;  // 64 x 16 tiles

    const unsigned short* Ag = A + (size_t)bm * 256 * K_DIM;
    const unsigned short* Bg = B + (size_t)bn * 256 * K_DIM;

    // staging lane pre-swizzle (inverse of the read XOR)
    const int lam = lane ^ (lane >> 3);
    const int rc = lam >> 3, cc = lam & 7;

    // read-side swizzled bases
    const int kx0 = (lg * 16) ^ ((lr & 7) << 4);
    const int aBase = (wm * 128 + lr) * 128 + kx0;
    const int bBase = 32768 + (wn * 64 + lr) * 128 + kx0;

    f32x4 acc[8][4] = {};
    bf16x8 arA[4][2], arB[4][2], br[4][2];

    // prologue: A(0)+B(0) -> buf0; drain; barrier
    STAGE(Ag, 0, 0, 0, 0);
    STAGE(Ag, 1, 0, 0, 0);
    STAGE(Bg, 0, 0, 0, 32768);
    STAGE(Bg, 1, 0, 0, 32768);
    asm volatile("s_waitcnt vmcnt(0)" ::: "memory");
    __builtin_amdgcn_s_barrier();
    CFENCE();

    for (int tt = 0; tt < NT; tt += 2) {
        KTILE(tt);
        KTILE(tt + 1);
    }

    // epilogue: D col = lane&15, row = (lane>>4)*4 + r (verified m89/m91)
    const int row0 = bm * 256 + wm * 128;
    const int col0 = bn * 256 + wn * 64;
#pragma unroll
    for (int n = 0; n < 4; ++n) {
        const int col = col0 + n * 16 + lr;
        const float bv = bias[col];
#pragma unroll
        for (int m = 0; m < 8; ++m) {
            const int r0 = row0 + m * 16 + lg * 4;
#pragma unroll
            for (int r = 0; r < 4; ++r)
                C[(size_t)(r0 + r) * N_DIM + col] = acc[m][n][r] + bv;
        }
    }
}

extern "C" void kernel_launch(void* const* d_in, const int* in_sizes, int n_in,
                              void* d_out, int out_size, void* d_ws, size_t ws_size,
                              hipStream_t stream) {
    const float* x    = (const float*)d_in[0];  // [4,4096,4096]
    const float* W    = (const float*)d_in[1];  // [4096,4096]
    const float* bias = (const float*)d_in[2];  // [4096]
    const float* lA   = (const float*)d_in[3];  // [16,4096]
    const float* lB   = (const float*)d_in[4];  // [4096,16]
    float* out = (float*)d_out;

    unsigned short* xb   = (unsigned short*)d_ws;                       // 134 MB
    unsigned short* weff = (unsigned short*)((char*)d_ws + 134217728);  // 32 MB

    cast_x_kernel<<<2048, 256, 0, stream>>>((const float4*)x, (u16x4*)xb,
                                            M_DIM * K_DIM / 4);
    weff_kernel<<<N_DIM, 256, 0, stream>>>(W, lA, lB, weff);
    gemm1b_kernel<<<(M_DIM / 256) * (N_DIM / 256), 512, 0, stream>>>(
        xb, weff, bias, out);
}

// Round 9
// 593.635 us; speedup vs baseline: 1.2337x; 1.1415x over previous
//
#include <hip/hip_runtime.h>
#include <hip/hip_bf16.h>

// LoRALinear: out = x @ (W + 2.0*B@A)^T + bias ; M=16384, N=4096, K=4096, R=16.
// Round 9: r6 base (best: 484us GEMM) + two coupled micro-fixes:
//  (1) move mh=1 A-reads AFTER the mid-barrier: halves become
//      16reads+32MFMA | 8reads+32MFMA instead of 24+0 | 0+64-ish split,
//      so LDS and MFMA demand are balanced within each barrier segment.
//  (2) single `ar` register set (drop arB): -32 live VGPRs. r8 post-mortem:
//      WRITE_SIZE excess over 268MB C = scratch spills; this trims them.
// Legality: mid-barrier only requires all B READS before it (B(t+2) restages
// bs.B); A reads of bs.A are safe after it (stages touch bs.B / bo.A only).
// ws layout: [0,134217728) x_bf16 ; [134217728, +33554432) W_eff_bf16.

typedef __attribute__((ext_vector_type(8))) short bf16x8;
typedef __attribute__((ext_vector_type(4))) float f32x4;
typedef __attribute__((ext_vector_type(4))) unsigned short u16x4;

#define M_DIM 16384
#define N_DIM 4096
#define K_DIM 4096
#define NT 64   // K-tiles of BK=64

__device__ __forceinline__ unsigned short f2bf(float f) {
    unsigned int u = __builtin_bit_cast(unsigned int, f);
    unsigned int r = u + 0x7FFFu + ((u >> 16) & 1u);
    return (unsigned short)(r >> 16);
}

__device__ __forceinline__ void async16(const void* g, void* l) {
    __builtin_amdgcn_global_load_lds(
        (const __attribute__((address_space(1))) unsigned int*)g,
        (__attribute__((address_space(3))) unsigned int*)l,
        16, 0, 0);
}

// ---------------- prep kernel 1: x fp32 -> bf16 ----------------
__global__ void __launch_bounds__(256) cast_x_kernel(
    const float4* __restrict__ x, u16x4* __restrict__ y, int n4) {
    int i = blockIdx.x * blockDim.x + threadIdx.x;
    int stride = gridDim.x * blockDim.x;
    for (; i < n4; i += stride) {
        float4 v = x[i];
        u16x4 o = { f2bf(v.x), f2bf(v.y), f2bf(v.z), f2bf(v.w) };
        y[i] = o;
    }
}

// ---------------- prep kernel 2: W_eff = W + 2*B@A -> bf16 ----------------
__global__ void __launch_bounds__(256) weff_kernel(
    const float* __restrict__ W, const float* __restrict__ lA,
    const float* __restrict__ lB, unsigned short* __restrict__ out) {
    constexpr int K = K_DIM, R = 16;
    constexpr float S = 2.0f;  // 32.0 / 16
    int o = blockIdx.x;
    int t = threadIdx.x;
    float b[R];
#pragma unroll
    for (int r = 0; r < R; ++r) b[r] = lB[o * R + r];
#pragma unroll
    for (int c = 0; c < 4; ++c) {
        int i = c * 1024 + t * 4;
        float4 wv = *reinterpret_cast<const float4*>(&W[o * K + i]);
        float sx = 0.f, sy = 0.f, sz = 0.f, sw = 0.f;
#pragma unroll
        for (int r = 0; r < R; ++r) {
            float4 a = *reinterpret_cast<const float4*>(&lA[r * K + i]);
            sx += b[r] * a.x; sy += b[r] * a.y;
            sz += b[r] * a.z; sw += b[r] * a.w;
        }
        u16x4 ov = { f2bf(wv.x + S * sx), f2bf(wv.y + S * sy),
                     f2bf(wv.z + S * sz), f2bf(wv.w + S * sw) };
        *reinterpret_cast<u16x4*>(&out[o * K + i]) = ov;
    }
}

// ---------------- main GEMM: 256x256 tile, 8-wave, 16x16x32 MFMA ----------------
// LDS (x2 dbuf): A tile 256x64 bf16 [0,32768) + B tile [32768,65536) per buf,
// 128B rows, XOR-swizzled: phys = row*128 + (colbyte ^ ((row&7)<<4)).
// Stage linear via global_load_lds with lane-pre-swizzled global source.
#define STAGE(G, h, tt, bsel, moff)                                           \
    do {                                                                      \
        const unsigned short* g0 = (G) +                                      \
            (size_t)((h) * 128 + wid * 16 + rc) * K_DIM + (tt) * 64 + cc * 8; \
        char* l0 = lds + (bsel) * 65536 + (moff) + (h) * 16384 + wid * 2048;  \
        async16(g0, l0);                                                      \
        async16(g0 + 8 * K_DIM, l0 + 1024);                                   \
    } while (0)

// fragment reads (round-2 pattern: measured 0 bank conflicts)
#define LDA_TO(dst, mh, bsel)                                                 \
    _Pragma("unroll") for (int mm = 0; mm < 4; ++mm)                          \
    _Pragma("unroll") for (int ks = 0; ks < 2; ++ks)                          \
        dst[mm][ks] = *(const bf16x8*)(lds + (bsel) * 65536 +                 \
            ((aBase + ((mh) * 4 + mm) * 2048) ^ (ks << 6)));

#define LDB_TO(nh, bsel)                                                      \
    _Pragma("unroll") for (int nn = 0; nn < 2; ++nn)                          \
    _Pragma("unroll") for (int ks = 0; ks < 2; ++ks)                          \
        br[(nh) * 2 + nn][ks] = *(const bf16x8*)(lds + (bsel) * 65536 +       \
            ((bBase + ((nh) * 2 + nn) * 2048) ^ (ks << 6)));

// one output quadrant: 16 MFMA using A-set `src` (mh) x B half (nh)
#define MM_Q(src, mh, nh)                                                     \
    __builtin_amdgcn_s_setprio(1);                                            \
    _Pragma("unroll") for (int ks = 0; ks < 2; ++ks)                          \
    _Pragma("unroll") for (int mm = 0; mm < 4; ++mm)                          \
    _Pragma("unroll") for (int nn = 0; nn < 2; ++nn)                          \
        acc[(mh) * 4 + mm][(nh) * 2 + nn] =                                   \
            __builtin_amdgcn_mfma_f32_16x16x32_bf16(                          \
                src[mm][ks], br[(nh) * 2 + nn][ks],                           \
                acc[(mh) * 4 + mm][(nh) * 2 + nn], 0, 0, 0);                  \
    __builtin_amdgcn_s_setprio(0)

#define CFENCE() asm volatile("" ::: "memory")

// one K-tile, balanced halves:
//   top:    stage A(t+1); 16 reads (A-mh0 + B-both); MM(0,0); MM(0,1)
//   mid-barrier (all B reads done -> bs.B restage safe)
//   bottom: stage B(t+2); 8 reads (A-mh1, overwrites ar); MM(1,0); MM(1,1)
//   boundary: counted vmcnt(4) retires A(t+1), keeps B(t+2); barrier
#define KTILE(t)                                                              \
    {                                                                         \
        const int bs_ = (t) & 1, bo_ = bs_ ^ 1;                               \
        if ((t) + 1 < NT) {                                                   \
            STAGE(Ag, 0, (t) + 1, bo_, 0);                                    \
            STAGE(Ag, 1, (t) + 1, bo_, 0);                                    \
        }                                                                     \
        LDA_TO(ar, 0, bs_);                                                   \
        LDB_TO(0, bs_);                                                       \
        LDB_TO(1, bs_);                                                       \
        MM_Q(ar, 0, 0);                                                       \
        MM_Q(ar, 0, 1);                                                       \
        CFENCE();                                                             \
        __builtin_amdgcn_s_barrier();                                         \
        CFENCE();                                                             \
        if ((t) + 2 < NT) STAGE(Bg, 0, (t) + 2, bs_, 32768);                  \
        LDA_TO(ar, 1, bs_);                                                   \
        MM_Q(ar, 1, 0);                                                       \
        if ((t) + 2 < NT) STAGE(Bg, 1, (t) + 2, bs_, 32768);                  \
        MM_Q(ar, 1, 1);                                                       \
        if ((t) < NT - 2) {                                                   \
            asm volatile("s_waitcnt vmcnt(4)" ::: "memory");                  \
        } else {                                                              \
            asm volatile("s_waitcnt vmcnt(0)" ::: "memory");                  \
        }                                                                     \
        __builtin_amdgcn_s_barrier();                                         \
        CFENCE();                                                             \
    }

__global__ void __launch_bounds__(512, 2) gemm2b_kernel(
    const unsigned short* __restrict__ A,
    const unsigned short* __restrict__ B,
    const float* __restrict__ bias,
    float* __restrict__ C) {
    __shared__ __align__(1024) char lds[131072];

    const int tid = threadIdx.x;
    const int lane = tid & 63, wid = tid >> 6;
    const int wm = wid >> 2, wn = wid & 3;   // 2 x 4 waves
    const int lr = lane & 15, lg = lane >> 4;

    // round-2 mapping: 1024 blocks, XCD-aware swizzle
    const int bid = blockIdx.x;
    const int swz = (bid & 7) * 128 + (bid >> 3);
    const int bm = swz >> 4, bn = swz & 15;  // 64 x 16 tiles

    const unsigned short* Ag = A + (size_t)bm * 256 * K_DIM;
    const unsigned short* Bg = B + (size_t)bn * 256 * K_DIM;

    // staging lane pre-swizzle (inverse of the read XOR)
    const int lam = lane ^ (lane >> 3);
    const int rc = lam >> 3, cc = lam & 7;

    // read-side swizzled bases
    const int kx0 = (lg * 16) ^ ((lr & 7) << 4);
    const int aBase = (wm * 128 + lr) * 128 + kx0;
    const int bBase = 32768 + (wn * 64 + lr) * 128 + kx0;

    f32x4 acc[8][4] = {};
    bf16x8 ar[4][2], br[4][2];

    // prologue: B(0), A(0) -> buf0 ; B(1) -> buf1
    STAGE(Bg, 0, 0, 0, 32768);
    STAGE(Bg, 1, 0, 0, 32768);
    STAGE(Ag, 0, 0, 0, 0);
    STAGE(Ag, 1, 0, 0, 0);
    STAGE(Bg, 0, 1, 1, 32768);
    STAGE(Bg, 1, 1, 1, 32768);
    asm volatile("s_waitcnt vmcnt(4)" ::: "memory");
    __builtin_amdgcn_s_barrier();
    CFENCE();

#pragma unroll 2
    for (int t = 0; t < NT; ++t) {
        KTILE(t);
    }

    // epilogue: D col = lane&15, row = (lane>>4)*4 + r (verified m89/m91)
    const int row0 = bm * 256 + wm * 128;
    const int col0 = bn * 256 + wn * 64;
#pragma unroll
    for (int n = 0; n < 4; ++n) {
        const int col = col0 + n * 16 + lr;
        const float bv = bias[col];
#pragma unroll
        for (int m = 0; m < 8; ++m) {
            const int r0 = row0 + m * 16 + lg * 4;
#pragma unroll
            for (int r = 0; r < 4; ++r)
                C[(size_t)(r0 + r) * N_DIM + col] = acc[m][n][r] + bv;
        }
    }
}

extern "C" void kernel_launch(void* const* d_in, const int* in_sizes, int n_in,
                              void* d_out, int out_size, void* d_ws, size_t ws_size,
                              hipStream_t stream) {
    const float* x    = (const float*)d_in[0];  // [4,4096,4096]
    const float* W    = (const float*)d_in[1];  // [4096,4096]
    const float* bias = (const float*)d_in[2];  // [4096]
    const float* lA   = (const float*)d_in[3];  // [16,4096]
    const float* lB   = (const float*)d_in[4];  // [4096,16]
    float* out = (float*)d_out;

    unsigned short* xb   = (unsigned short*)d_ws;                       // 134 MB
    unsigned short* weff = (unsigned short*)((char*)d_ws + 134217728);  // 32 MB

    cast_x_kernel<<<2048, 256, 0, stream>>>((const float4*)x, (u16x4*)xb,
                                            M_DIM * K_DIM / 4);
    weff_kernel<<<N_DIM, 256, 0, stream>>>(W, lA, lB, weff);
    gemm2b_kernel<<<(M_DIM / 256) * (N_DIM / 256), 512, 0, stream>>>(
        xb, weff, bias, out);
}

// Round 10
// 593.237 us; speedup vs baseline: 1.2345x; 1.0007x over previous
//
#include <hip/hip_runtime.h>
#include <hip/hip_bf16.h>

// LoRALinear: out = x @ (W + 2.0*B@A)^T + bias ; M=16384, N=4096, K=4096, R=16.
// Round 10: r6 chassis (best 484us) + ks-split balanced read groups with
// 1-cluster-ahead issue and counted lgkmcnt (+sched_barrier, rule #18).
// Clusters per K-tile: (mh0,ks0),(mh1,ks0),(mh0,ks1),(mh1,ks1); read groups
// G0(8)/G1(4)/G2(8)/G3(4) issue one cluster ahead; waits lgkmcnt(4/8/4/0).
// Staging/vmcnt identical to r6 (A(t+1)->bo, B(t+2)->bs, mid-barrier after
// all B reads retired, boundary vmcnt(4) retiring B(t+1)+A(t+1)).
// ws layout: [0,134217728) x_bf16 ; [134217728, +33554432) W_eff_bf16.

typedef __attribute__((ext_vector_type(8))) short bf16x8;
typedef __attribute__((ext_vector_type(4))) float f32x4;
typedef __attribute__((ext_vector_type(4))) unsigned short u16x4;

#define M_DIM 16384
#define N_DIM 4096
#define K_DIM 4096
#define NT 64   // K-tiles of BK=64

__device__ __forceinline__ unsigned short f2bf(float f) {
    unsigned int u = __builtin_bit_cast(unsigned int, f);
    unsigned int r = u + 0x7FFFu + ((u >> 16) & 1u);
    return (unsigned short)(r >> 16);
}

__device__ __forceinline__ void async16(const void* g, void* l) {
    __builtin_amdgcn_global_load_lds(
        (const __attribute__((address_space(1))) unsigned int*)g,
        (__attribute__((address_space(3))) unsigned int*)l,
        16, 0, 0);
}

// ---------------- prep kernel 1: x fp32 -> bf16 ----------------
__global__ void __launch_bounds__(256) cast_x_kernel(
    const float4* __restrict__ x, u16x4* __restrict__ y, int n4) {
    int i = blockIdx.x * blockDim.x + threadIdx.x;
    int stride = gridDim.x * blockDim.x;
    for (; i < n4; i += stride) {
        float4 v = x[i];
        u16x4 o = { f2bf(v.x), f2bf(v.y), f2bf(v.z), f2bf(v.w) };
        y[i] = o;
    }
}

// ---------------- prep kernel 2: W_eff = W + 2*B@A -> bf16 ----------------
__global__ void __launch_bounds__(256) weff_kernel(
    const float* __restrict__ W, const float* __restrict__ lA,
    const float* __restrict__ lB, unsigned short* __restrict__ out) {
    constexpr int K = K_DIM, R = 16;
    constexpr float S = 2.0f;  // 32.0 / 16
    int o = blockIdx.x;
    int t = threadIdx.x;
    float b[R];
#pragma unroll
    for (int r = 0; r < R; ++r) b[r] = lB[o * R + r];
#pragma unroll
    for (int c = 0; c < 4; ++c) {
        int i = c * 1024 + t * 4;
        float4 wv = *reinterpret_cast<const float4*>(&W[o * K + i]);
        float sx = 0.f, sy = 0.f, sz = 0.f, sw = 0.f;
#pragma unroll
        for (int r = 0; r < R; ++r) {
            float4 a = *reinterpret_cast<const float4*>(&lA[r * K + i]);
            sx += b[r] * a.x; sy += b[r] * a.y;
            sz += b[r] * a.z; sw += b[r] * a.w;
        }
        u16x4 ov = { f2bf(wv.x + S * sx), f2bf(wv.y + S * sy),
                     f2bf(wv.z + S * sz), f2bf(wv.w + S * sw) };
        *reinterpret_cast<u16x4*>(&out[o * K + i]) = ov;
    }
}

// ---------------- main GEMM: 256x256 tile, 8-wave, 16x16x32 MFMA ----------------
// LDS (x2 dbuf): A tile 256x64 bf16 [0,32768) + B tile [32768,65536) per buf,
// 128B rows, XOR-swizzled: phys = row*128 + (colbyte ^ ((row&7)<<4)).
#define STAGE(G, h, tt, bsel, moff)                                           \
    do {                                                                      \
        const unsigned short* g0 = (G) +                                      \
            (size_t)((h) * 128 + wid * 16 + rc) * K_DIM + (tt) * 64 + cc * 8; \
        char* l0 = lds + (bsel) * 65536 + (moff) + (h) * 16384 + wid * 2048;  \
        async16(g0, l0);                                                      \
        async16(g0 + 8 * K_DIM, l0 + 1024);                                   \
    } while (0)

// single-ks fragment reads (addresses identical to r6: measured 0 conflicts)
#define LDA_KS(dst, mh, ks, bsel)                                             \
    _Pragma("unroll") for (int mm = 0; mm < 4; ++mm)                          \
        dst[mm] = *(const bf16x8*)(lds + (bsel) * 65536 +                     \
            ((aBase + ((mh) * 4 + mm) * 2048) ^ ((ks) << 6)));

#define LDB_KS(ks, bsel)                                                      \
    _Pragma("unroll") for (int nn = 0; nn < 4; ++nn)                          \
        br[nn][ks] = *(const bf16x8*)(lds + (bsel) * 65536 +                  \
            ((bBase + nn * 2048) ^ ((ks) << 6)));

// one cluster: 16 MFMA, fixed ks, A-set src (4 frags), all 4 n-frags
#define MMQ_KS(src, mh, ks)                                                   \
    __builtin_amdgcn_s_setprio(1);                                            \
    _Pragma("unroll") for (int mm = 0; mm < 4; ++mm)                          \
    _Pragma("unroll") for (int nn = 0; nn < 4; ++nn)                          \
        acc[(mh) * 4 + mm][nn] = __builtin_amdgcn_mfma_f32_16x16x32_bf16(     \
            src[mm], br[nn][ks], acc[(mh) * 4 + mm][nn], 0, 0, 0);            \
    __builtin_amdgcn_s_setprio(0)

#define CFENCE() asm volatile("" ::: "memory")
#define WAIT_LGKM(n)                                                          \
    asm volatile("s_waitcnt lgkmcnt(" #n ")" ::: "memory");                   \
    __builtin_amdgcn_sched_barrier(0)

// K-tile: clusters pipelined one read-group ahead.
// lgkm queue walk (per wave): G0(8) G1(4) -> wait(4)=G0 done; G2(8) ->
// wait(8)=G1 done; G3(4) -> wait(4)=G2 done; wait(0)=G3 done.
#define KTILE(t)                                                              \
    {                                                                         \
        const int bs_ = (t) & 1, bo_ = bs_ ^ 1;                               \
        LDA_KS(arE, 0, 0, bs_);            /* G0a: 4 */                       \
        LDB_KS(0, bs_);                    /* G0b: 4 */                       \
        if ((t) + 1 < NT) STAGE(Ag, 0, (t) + 1, bo_, 0);                      \
        LDA_KS(arO, 1, 0, bs_);            /* G1: 4 */                        \
        WAIT_LGKM(4);                                                         \
        MMQ_KS(arE, 0, 0);                                                    \
        if ((t) + 1 < NT) STAGE(Ag, 1, (t) + 1, bo_, 0);                      \
        LDA_KS(arE, 0, 1, bs_);            /* G2a: 4 (arE WAR after M0) */    \
        LDB_KS(1, bs_);                    /* G2b: 4 */                       \
        WAIT_LGKM(8);                                                         \
        MMQ_KS(arO, 1, 0);                                                    \
        LDA_KS(arO, 1, 1, bs_);            /* G3: 4 */                        \
        WAIT_LGKM(4);                                                         \
        MMQ_KS(arE, 0, 1);                                                    \
        CFENCE();                                                             \
        __builtin_amdgcn_s_barrier();  /* all B reads retired (G2 waited) */  \
        CFENCE();                                                             \
        if ((t) + 2 < NT) STAGE(Bg, 0, (t) + 2, bs_, 32768);                  \
        WAIT_LGKM(0);                                                         \
        MMQ_KS(arO, 1, 1);                                                    \
        if ((t) + 2 < NT) STAGE(Bg, 1, (t) + 2, bs_, 32768);                  \
        if ((t) < NT - 2) {                                                   \
            asm volatile("s_waitcnt vmcnt(4)" ::: "memory");                  \
        } else {                                                              \
            asm volatile("s_waitcnt vmcnt(0)" ::: "memory");                  \
        }                                                                     \
        __builtin_amdgcn_s_barrier();                                         \
        CFENCE();                                                             \
    }

__global__ void __launch_bounds__(512, 2) gemmks_kernel(
    const unsigned short* __restrict__ A,
    const unsigned short* __restrict__ B,
    const float* __restrict__ bias,
    float* __restrict__ C) {
    __shared__ __align__(1024) char lds[131072];

    const int tid = threadIdx.x;
    const int lane = tid & 63, wid = tid >> 6;
    const int wm = wid >> 2, wn = wid & 3;   // 2 x 4 waves
    const int lr = lane & 15, lg = lane >> 4;

    // round-2 mapping: 1024 blocks, XCD-aware swizzle
    const int bid = blockIdx.x;
    const int swz = (bid & 7) * 128 + (bid >> 3);
    const int bm = swz >> 4, bn = swz & 15;  // 64 x 16 tiles

    const unsigned short* Ag = A + (size_t)bm * 256 * K_DIM;
    const unsigned short* Bg = B + (size_t)bn * 256 * K_DIM;

    // staging lane pre-swizzle (inverse of the read XOR)
    const int lam = lane ^ (lane >> 3);
    const int rc = lam >> 3, cc = lam & 7;

    // read-side swizzled bases
    const int kx0 = (lg * 16) ^ ((lr & 7) << 4);
    const int aBase = (wm * 128 + lr) * 128 + kx0;
    const int bBase = 32768 + (wn * 64 + lr) * 128 + kx0;

    f32x4 acc[8][4] = {};
    bf16x8 arE[4], arO[4], br[4][2];

    // prologue: B(0), A(0) -> buf0 ; B(1) -> buf1 ; vmcnt(4) retires B(0)+A(0)
    STAGE(Bg, 0, 0, 0, 32768);
    STAGE(Bg, 1, 0, 0, 32768);
    STAGE(Ag, 0, 0, 0, 0);
    STAGE(Ag, 1, 0, 0, 0);
    STAGE(Bg, 0, 1, 1, 32768);
    STAGE(Bg, 1, 1, 1, 32768);
    asm volatile("s_waitcnt vmcnt(4)" ::: "memory");
    __builtin_amdgcn_s_barrier();
    CFENCE();

#pragma unroll 2
    for (int t = 0; t < NT; ++t) {
        KTILE(t);
    }

    // epilogue: D col = lane&15, row = (lane>>4)*4 + r (verified m89/m91)
    const int row0 = bm * 256 + wm * 128;
    const int col0 = bn * 256 + wn * 64;
#pragma unroll
    for (int n = 0; n < 4; ++n) {
        const int col = col0 + n * 16 + lr;
        const float bv = bias[col];
#pragma unroll
        for (int m = 0; m < 8; ++m) {
            const int r0 = row0 + m * 16 + lg * 4;
#pragma unroll
            for (int r = 0; r < 4; ++r)
                C[(size_t)(r0 + r) * N_DIM + col] = acc[m][n][r] + bv;
        }
    }
}

extern "C" void kernel_launch(void* const* d_in, const int* in_sizes, int n_in,
                              void* d_out, int out_size, void* d_ws, size_t ws_size,
                              hipStream_t stream) {
    const float* x    = (const float*)d_in[0];  // [4,4096,4096]
    const float* W    = (const float*)d_in[1];  // [4096,4096]
    const float* bias = (const float*)d_in[2];  // [4096]
    const float* lA   = (const float*)d_in[3];  // [16,4096]
    const float* lB   = (const float*)d_in[4];  // [4096,16]
    float* out = (float*)d_out;

    unsigned short* xb   = (unsigned short*)d_ws;                       // 134 MB
    unsigned short* weff = (unsigned short*)((char*)d_ws + 134217728);  // 32 MB

    cast_x_kernel<<<2048, 256, 0, stream>>>((const float4*)x, (u16x4*)xb,
                                            M_DIM * K_DIM / 4);
    weff_kernel<<<N_DIM, 256, 0, stream>>>(W, lA, lB, weff);
    gemmks_kernel<<<(M_DIM / 256) * (N_DIM / 256), 512, 0, stream>>>(
        xb, weff, bias, out);
}